// Round 4
// baseline (25.161 us; speedup 1.0000x reference)
//
#include <hip/hip_runtime.h>

// Potts model: out[b] = sum_t coeffs[t] * (x[b,idx[t,0..3]] all equal)
// B=2048, N=4096, T=8192, K=4, states are exact floats in {0.0,1.0,2.0}.
//
// v4: two-kernel pipeline.
//  pack_kernel:   x (33.5 MB f32) -> pk (2 MB, u32 per column holding 16 rows
//                 at 2 bits each; (bits>>29)&3 is injective on {0,1,2}).
//                 Pure stream, HBM-floor bound.
//  gather_kernel: 128 b-groups x 4 t-chunks = 512 blocks (2/CU). Each stages
//                 16 KB of pk into LDS, gathers 4 random u32s per t, XOR-trick
//                 all-equal for 16 rows at once, atomicAdd 4 partials/output.
// Rationale: r3's single kernel serialized stage->gather on every CU with
// grid=256. The 2 MB packed intermediate makes t-splitting affordable
// (gather work per CU drops 4x) and 2 blocks/CU overlap the phases.

#define NN 4096
#define BB 2048
#define TT 8192
#define G 16
#define NBG (BB / G)            // 128 b-groups
#define PKT 256                 // pack block threads
#define PK_CHUNK 1024           // columns packed per pack block
#define PK_GRID (NBG * (NN / PK_CHUNK))   // 512
#define GT 512                  // gather block threads
#define TS 4                    // t-split
#define G_GRID (NBG * TS)       // 512
#define TPT (TT / TS / GT)      // 4 t's per gather thread

typedef unsigned int u32;

__device__ __forceinline__ u32 code2(float f) {
    // {0x00000000, 0x3F800000, 0x40000000} >> 29 & 3 -> {0, 1, 2}
    return (__float_as_uint(f) >> 29) & 3u;
}

__global__ __launch_bounds__(PKT) void pack_kernel(
    const float* __restrict__ x, u32* __restrict__ pk)
{
    const int bg = blockIdx.x >> 2;            // NN/PK_CHUNK = 4 chunks
    const int ch = blockIdx.x & 3;
    const int n0 = ch * PK_CHUNK + threadIdx.x * 4;
    u32 w0 = 0, w1 = 0, w2 = 0, w3 = 0;
    #pragma unroll
    for (int g = 0; g < G; ++g) {
        const float4 f =
            *reinterpret_cast<const float4*>(x + (size_t)(bg * G + g) * NN + n0);
        w0 |= code2(f.x) << (2 * g);
        w1 |= code2(f.y) << (2 * g);
        w2 |= code2(f.z) << (2 * g);
        w3 |= code2(f.w) << (2 * g);
    }
    *reinterpret_cast<uint4*>(pk + (size_t)bg * NN + n0) = make_uint4(w0, w1, w2, w3);
}

__global__ __launch_bounds__(GT) void gather_kernel(
    const u32* __restrict__ pk, const float* __restrict__ coeffs,
    const int* __restrict__ idx, float* __restrict__ out)
{
    __shared__ u32 xs[NN];                     // 16 KB
    __shared__ float red[GT / 64][G];

    const int tid = threadIdx.x;
    const int bg  = blockIdx.x >> 2;           // TS = 4
    const int th  = blockIdx.x & 3;

    // Preload this block's idx/coeff slice (fully unrolled -> VGPRs, rule #20).
    int4  ii[TPT];
    float cf[TPT];
    const int tbase = th * (TT / TS);
    #pragma unroll
    for (int i = 0; i < TPT; ++i) {
        const int t = tbase + tid + i * GT;
        ii[i] = *reinterpret_cast<const int4*>(idx + 4 * t);
        cf[i] = coeffs[t];
    }

    // Stage this b-group's packed columns (16 KB) into LDS.
    #pragma unroll
    for (int k = 0; k < NN / 4 / GT; ++k) {    // 2 iterations of uint4
        const int c = tid + k * GT;
        reinterpret_cast<uint4*>(xs)[c] =
            reinterpret_cast<const uint4*>(pk + (size_t)bg * NN)[c];
    }
    __syncthreads();

    float acc[G];
    #pragma unroll
    for (int g = 0; g < G; ++g) acc[g] = 0.f;

    #pragma unroll
    for (int i = 0; i < TPT; ++i) {
        const u32 a = xs[ii[i].x];
        const u32 b = xs[ii[i].y];
        const u32 c = xs[ii[i].z];
        const u32 d = xs[ii[i].w];
        const u32 diff = (a ^ b) | (a ^ c) | (a ^ d);
        const u32 m = diff | (diff >> 1);      // bit 2g set <=> group g differs
        const float cv = cf[i];
        #pragma unroll
        for (int g = 0; g < G; ++g)
            acc[g] += ((m >> (2 * g)) & 1u) ? 0.f : cv;
    }

    // Block reduction: wave shuffle, then tiny LDS reduce, then 4-way atomic.
    #pragma unroll
    for (int g = 0; g < G; ++g) {
        float v = acc[g];
        #pragma unroll
        for (int off = 32; off > 0; off >>= 1) v += __shfl_down(v, off, 64);
        if ((tid & 63) == 0) red[tid >> 6][g] = v;
    }
    __syncthreads();

    if (tid < G) {
        float s = 0.f;
        #pragma unroll
        for (int w = 0; w < GT / 64; ++w) s += red[w][tid];
        atomicAdd(&out[bg * G + tid], s);
    }
}

extern "C" void kernel_launch(void* const* d_in, const int* in_sizes, int n_in,
                              void* d_out, int out_size, void* d_ws, size_t ws_size,
                              hipStream_t stream) {
    const float* x      = (const float*)d_in[0];   // [B, N] f32
    const float* coeffs = (const float*)d_in[1];   // [T] f32
    const int*   idx    = (const int*)d_in[2];     // [T, 4] i32

    float* out = (float*)d_out;                    // [B] f32
    u32*   pk  = (u32*)d_ws;                       // 2 MB packed x

    hipMemsetAsync(d_out, 0, (size_t)out_size * sizeof(float), stream);
    pack_kernel<<<PK_GRID, PKT, 0, stream>>>(x, pk);
    gather_kernel<<<G_GRID, GT, 0, stream>>>(pk, coeffs, idx, out);
}

// Round 5
// 14.186 us; speedup vs baseline: 1.7737x; 1.7737x over previous
//
#include <hip/hip_runtime.h>

// Potts model: out[b] = sum_t coeffs[t] * (x[b,idx[t,0..3]] all equal)
// B=2048, N=4096, T=8192, K=4, states are exact floats in {0.0,1.0,2.0}.
//
// v5: revert to v3's single-kernel structure (v4's 3-dispatch split paid
// per-node graph overhead and regressed). Single change vs v3: 1024-thread
// blocks (16 waves/CU instead of 8) to hide stream + LDS-gather latency.
// Per-CU work identical; per-thread work halves (8 stream loads, 8 gathers).

#define NN 4096
#define TT 8192
#define G 8
#define THREADS 1024
#define TPT (TT / THREADS)   // 8 t's per thread (compile-time)

typedef unsigned long long u64;
typedef unsigned int u32;
typedef unsigned short u16;

__device__ __forceinline__ u32 code2(float f) {
    // {0x00000000, 0x3F800000, 0x40000000} >> 29 & 3 -> {0, 1, 2}
    return (__float_as_uint(f) >> 29) & 3u;
}

__global__ __launch_bounds__(THREADS) void potts_kernel(
    const float* __restrict__ x,
    const float* __restrict__ coeffs,
    const int*   __restrict__ idx,
    float*       __restrict__ out)
{
    __shared__ u16 xs[NN];                 // 8 KB
    __shared__ float red[THREADS / 64][G];

    const int tid = threadIdx.x;
    const int b0  = blockIdx.x * G;

    // Preload this thread's idx/coeff slice (fully unrolled -> VGPRs).
    int4  ii[TPT];
    float cf[TPT];
    #pragma unroll
    for (int i = 0; i < TPT; ++i) {
        const int t = tid + i * THREADS;
        ii[i] = *reinterpret_cast<const int4*>(idx + 4 * t);
        cf[i] = coeffs[t];
    }

    // Stage G rows, 2-bit packed. NN/4 == THREADS: each thread packs its own
    // 4 consecutive columns across all 8 rows -> one aligned ds_write_b64.
    {
        const int n0 = tid * 4;
        u64 v = 0;
        #pragma unroll
        for (int g = 0; g < G; ++g) {
            const float4 f =
                *reinterpret_cast<const float4*>(x + (size_t)(b0 + g) * NN + n0);
            v |= (u64)(code2(f.x) << (2 * g));
            v |= (u64)(code2(f.y) << (2 * g)) << 16;
            v |= (u64)(code2(f.z) << (2 * g)) << 32;
            v |= (u64)(code2(f.w) << (2 * g)) << 48;
        }
        reinterpret_cast<u64*>(xs)[tid] = v;
    }
    __syncthreads();

    float acc[G];
    #pragma unroll
    for (int g = 0; g < G; ++g) acc[g] = 0.f;

    #pragma unroll            // FULL unroll: static ii[i]/cf[i] indices
    for (int i = 0; i < TPT; ++i) {
        const u32 a = xs[ii[i].x];
        const u32 b = xs[ii[i].y];
        const u32 c = xs[ii[i].z];
        const u32 d = xs[ii[i].w];
        const u32 diff = (a ^ b) | (a ^ c) | (a ^ d);
        const u32 m = diff | (diff >> 1);   // bit 2g set <=> clique g differs
        const float cv = cf[i];
        #pragma unroll
        for (int g = 0; g < G; ++g)
            acc[g] += ((m >> (2 * g)) & 1u) ? 0.f : cv;
    }

    // Block reduction: wave shuffle, then tiny LDS reduce.
    #pragma unroll
    for (int g = 0; g < G; ++g) {
        float v = acc[g];
        #pragma unroll
        for (int off = 32; off > 0; off >>= 1) v += __shfl_down(v, off, 64);
        if ((tid & 63) == 0) red[tid >> 6][g] = v;
    }
    __syncthreads();

    if (tid < G) {
        float s = 0.f;
        #pragma unroll
        for (int w = 0; w < THREADS / 64; ++w) s += red[w][tid];
        out[b0 + tid] = s;
    }
}

extern "C" void kernel_launch(void* const* d_in, const int* in_sizes, int n_in,
                              void* d_out, int out_size, void* d_ws, size_t ws_size,
                              hipStream_t stream) {
    const float* x      = (const float*)d_in[0];   // [B, N] f32
    const float* coeffs = (const float*)d_in[1];   // [T] f32
    const int*   idx    = (const int*)d_in[2];     // [T, 4] i32

    float* out = (float*)d_out;                    // [B] f32

    const int Bn   = in_sizes[0] / NN;             // 2048
    const int grid = Bn / G;                       // 256 blocks, 1/CU

    potts_kernel<<<grid, THREADS, 0, stream>>>(x, coeffs, idx, out);
}